// Round 1
// baseline (645.108 us; speedup 1.0000x reference)
//
#include <hip/hip_runtime.h>
#include <hip/hip_bf16.h>
#include <stdint.h>

#define N_NODES 8192
#define DIM 256

typedef __attribute__((ext_vector_type(8))) __bf16 bf16x8;
typedef __attribute__((ext_vector_type(4))) float f32x4;

__device__ __forceinline__ unsigned short f2bf(float f) {
  unsigned u = __builtin_bit_cast(unsigned, f);
  u += 0x7fffu + ((u >> 16) & 1u);
  return (unsigned short)(u >> 16);
}
__device__ __forceinline__ float bf2f(unsigned short h) {
  return __builtin_bit_cast(float, (unsigned)h << 16);
}

// ---------------------------------------------------------------------------
// Kernel 1: d_inv_sqrt[i] = rsqrt(sum_j adj[i,j] + 1)
// One block (256 thr) per row; 8 float4 loads per thread, coalesced.
// ---------------------------------------------------------------------------
__global__ __launch_bounds__(256) void rowsum_kernel(const float* __restrict__ adj,
                                                     float* __restrict__ dinv) {
  int row = blockIdx.x;
  const float4* r = (const float4*)(adj + (size_t)row * N_NODES);
  float s = 0.f;
#pragma unroll
  for (int it = 0; it < 8; ++it) {
    float4 v = r[threadIdx.x + it * 256];
    s += (v.x + v.y) + (v.z + v.w);
  }
#pragma unroll
  for (int off = 32; off > 0; off >>= 1) s += __shfl_down(s, off);
  __shared__ float red[4];
  if ((threadIdx.x & 63) == 0) red[threadIdx.x >> 6] = s;
  __syncthreads();
  if (threadIdx.x == 0) {
    float tot = red[0] + red[1] + red[2] + red[3] + 1.0f;
    dinv[row] = rsqrtf(tot);
  }
}

// ---------------------------------------------------------------------------
// Kernel 2: t[j,k] = d_j * (x @ W^T)[j,k]  (fp32 compute, bf16 store)
// Writes tT [DIM][N_NODES] (B-operand for GEMM) and trm [N_NODES][DIM].
// Block: 256 thr (thread = output col n), j-tile of 32 rows in LDS. 256 blocks.
// ---------------------------------------------------------------------------
__global__ __launch_bounds__(256) void support_kernel(
    const float* __restrict__ x, const float* __restrict__ W,
    const float* __restrict__ dinv,
    unsigned short* __restrict__ tT, unsigned short* __restrict__ trm) {
  __shared__ float4 xs[32 * 64];  // x[j0+j][c] as float4: [j][c4]
  __shared__ float djs[32];
  int tid = threadIdx.x;
  int j0 = blockIdx.x * 32;
  const float4* xg = (const float4*)(x + (size_t)j0 * DIM);
#pragma unroll
  for (int it = 0; it < 8; ++it) xs[tid + it * 256] = xg[tid + it * 256];
  if (tid < 32) djs[tid] = dinv[j0 + tid];
  __syncthreads();

  int n = tid;
  float acc[32];
#pragma unroll
  for (int j = 0; j < 32; ++j) acc[j] = 0.f;
  const float4* wrow = (const float4*)(W + (size_t)n * DIM);
#pragma unroll 1
  for (int cc = 0; cc < 4; ++cc) {
    float4 wr[16];
#pragma unroll
    for (int m = 0; m < 16; ++m) wr[m] = wrow[cc * 16 + m];
#pragma unroll
    for (int j = 0; j < 32; ++j) {
      float s = 0.f;
#pragma unroll
      for (int m = 0; m < 16; ++m) {
        float4 xv = xs[j * 64 + cc * 16 + m];  // broadcast: all lanes same addr
        s += xv.x * wr[m].x + xv.y * wr[m].y + xv.z * wr[m].z + xv.w * wr[m].w;
      }
      acc[j] += s;
    }
  }
  size_t nrow = (size_t)n * N_NODES;
#pragma unroll
  for (int j = 0; j < 32; ++j) {
    unsigned short b = f2bf(acc[j] * djs[j]);
    tT[nrow + j0 + j] = b;                      // transposed (for GEMM B)
    trm[(size_t)(j0 + j) * DIM + n] = b;        // row-major (for epilogue)
  }
}

// ---------------------------------------------------------------------------
// Kernel 3: split-K GEMM  part[s][i,k] = sum_{j in chunk s} bf16(adj[i,j])*t[j,k]
// Block tile: 64(M) x 256(N full) x BK=32, 4 waves (each 64x64 = 4x4 frags of
// 16x16x32 bf16 MFMA). adj fp32 loaded+cvt'd to bf16 into LDS; tT bf16 staged
// [n][k] so B-frags are contiguous ds_read_b128. Rows padded to 40 elems.
// Grid: (128 M-blocks, S k-chunks).
// ---------------------------------------------------------------------------
#define AROW 40  // padded LDS row (bf16 elems): 80 B -> <=2-way bank aliasing
__global__ __launch_bounds__(256, 2) void gemm_kernel(
    const float* __restrict__ adj, const unsigned short* __restrict__ tT,
    float* __restrict__ part, int KC) {
  __shared__ unsigned short Al[64 * AROW];    // [m][k]
  __shared__ unsigned short Bl[256 * AROW];   // [n][k]
  int tid = threadIdx.x;
  int lane = tid & 63, wave = tid >> 6;
  int bx = blockIdx.x, s = blockIdx.y;
  size_t i0 = (size_t)bx * 64;
  int kbase = s * KC;

  // staging roles
  int am = tid >> 2, ak = tid & 3;            // A: row m=am, k-octet ak
  const float* ag = adj + (i0 + am) * (size_t)N_NODES + ak * 8;
  int bn = tid >> 2, bk = tid & 3;            // B: n = q*64+bn, k-octet bk

  f32x4 acc[4][4];
#pragma unroll
  for (int mf = 0; mf < 4; ++mf)
#pragma unroll
    for (int nf = 0; nf < 4; ++nf) acc[mf][nf] = (f32x4){0.f, 0.f, 0.f, 0.f};

  int arow = lane & 15, akq = lane >> 4;      // fragment lane decode

  for (int kk = 0; kk < KC; kk += 32) {
    const int k0 = kbase + kk;
    // global loads first (overlap with prior compute before the barrier)
    float4 av0 = *(const float4*)(ag + k0);
    float4 av1 = *(const float4*)(ag + k0 + 4);
    uint4 bv[4];
#pragma unroll
    for (int q = 0; q < 4; ++q) {
      int n = q * 64 + bn;
      bv[q] = *(const uint4*)(tT + (size_t)n * N_NODES + k0 + bk * 8);
    }
    __syncthreads();  // previous iter's LDS reads done
    unsigned p0 = f2bf(av0.x) | ((unsigned)f2bf(av0.y) << 16);
    unsigned p1 = f2bf(av0.z) | ((unsigned)f2bf(av0.w) << 16);
    unsigned p2 = f2bf(av1.x) | ((unsigned)f2bf(av1.y) << 16);
    unsigned p3 = f2bf(av1.z) | ((unsigned)f2bf(av1.w) << 16);
    *(uint4*)&Al[am * AROW + ak * 8] = make_uint4(p0, p1, p2, p3);
#pragma unroll
    for (int q = 0; q < 4; ++q)
      *(uint4*)&Bl[(q * 64 + bn) * AROW + bk * 8] = bv[q];
    __syncthreads();

    bf16x8 a[4], b[4];
#pragma unroll
    for (int mf = 0; mf < 4; ++mf)
      a[mf] = *reinterpret_cast<const bf16x8*>(&Al[(mf * 16 + arow) * AROW + akq * 8]);
#pragma unroll
    for (int nf = 0; nf < 4; ++nf)
      b[nf] = *reinterpret_cast<const bf16x8*>(&Bl[(wave * 64 + nf * 16 + arow) * AROW + akq * 8]);
#pragma unroll
    for (int mf = 0; mf < 4; ++mf)
#pragma unroll
      for (int nf = 0; nf < 4; ++nf)
        acc[mf][nf] = __builtin_amdgcn_mfma_f32_16x16x32_bf16(a[mf], b[nf], acc[mf][nf], 0, 0, 0);
  }

  // epilogue: raw partial sums (no scaling here)
  float* pb = part + (size_t)s * ((size_t)N_NODES * DIM);
  int crow = (lane >> 4) * 4;
  int ccol = lane & 15;
#pragma unroll
  for (int mf = 0; mf < 4; ++mf)
#pragma unroll
    for (int nf = 0; nf < 4; ++nf) {
      size_t rbase = (i0 + mf * 16 + crow) * (size_t)DIM + wave * 64 + nf * 16 + ccol;
#pragma unroll
      for (int r = 0; r < 4; ++r) pb[rbase + (size_t)r * DIM] = acc[mf][nf][r];
    }
}

// ---------------------------------------------------------------------------
// Kernel 4: out[i,k] = relu(d_i * (sum_s part[s][i,k] + trm[i,k]))
// ---------------------------------------------------------------------------
__global__ __launch_bounds__(256) void reduce_kernel(
    const float* __restrict__ part, const unsigned short* __restrict__ trm,
    const float* __restrict__ dinv, float* __restrict__ out, int S) {
  size_t idx = ((size_t)blockIdx.x * 256 + threadIdx.x) * 4;
  int i = (int)(idx >> 8);
  float4 v = *(const float4*)(part + idx);
  for (int s = 1; s < S; ++s) {
    float4 p = *(const float4*)(part + (size_t)s * ((size_t)N_NODES * DIM) + idx);
    v.x += p.x; v.y += p.y; v.z += p.z; v.w += p.w;
  }
  ushort4 t = *(const ushort4*)(trm + idx);
  float d = dinv[i];
  float4 o;
  o.x = fmaxf(0.f, d * (v.x + bf2f(t.x)));
  o.y = fmaxf(0.f, d * (v.y + bf2f(t.y)));
  o.z = fmaxf(0.f, d * (v.z + bf2f(t.z)));
  o.w = fmaxf(0.f, d * (v.w + bf2f(t.w)));
  *(float4*)(out + idx) = o;
}

// ---------------------------------------------------------------------------
extern "C" void kernel_launch(void* const* d_in, const int* in_sizes, int n_in,
                              void* d_out, int out_size, void* d_ws, size_t ws_size,
                              hipStream_t stream) {
  const float* x = (const float*)d_in[0];
  const float* adj = (const float*)d_in[1];
  const float* W = (const float*)d_in[2];
  float* out = (float*)d_out;
  char* ws = (char*)d_ws;

  // ws layout: dinv (32 KiB) | tT (4 MiB) | trm (4 MiB) | partials (S x 8 MiB)
  float* dinv = (float*)ws;
  unsigned short* tT = (unsigned short*)(ws + 32768);
  unsigned short* trm = (unsigned short*)(ws + 32768 + (size_t)N_NODES * DIM * 2);
  size_t base = 32768 + 2 * (size_t)N_NODES * DIM * 2;
  size_t pbytes = (size_t)N_NODES * DIM * 4;

  int S;
  float* part;
  if (base + 4 * pbytes <= ws_size) { S = 4; part = (float*)(ws + base); }
  else if (base + 2 * pbytes <= ws_size) { S = 2; part = (float*)(ws + base); }
  else if (base + 1 * pbytes <= ws_size) { S = 1; part = (float*)(ws + base); }
  else { S = 1; part = out; }  // in-place fallback: reduce reads+writes d_out

  rowsum_kernel<<<N_NODES, 256, 0, stream>>>(adj, dinv);
  support_kernel<<<N_NODES / 32, 256, 0, stream>>>(x, W, dinv, tT, trm);
  gemm_kernel<<<dim3(N_NODES / 64, S), 256, 0, stream>>>(adj, tT, part, N_NODES / S);
  reduce_kernel<<<(N_NODES * DIM) / 1024, 256, 0, stream>>>(part, trm, dinv, out, S);
}

// Round 2
// 601.560 us; speedup vs baseline: 1.0724x; 1.0724x over previous
//
#include <hip/hip_runtime.h>
#include <hip/hip_bf16.h>
#include <stdint.h>

#define N_NODES 8192
#define DIM 256

typedef __attribute__((ext_vector_type(8))) __bf16 bf16x8;
typedef __attribute__((ext_vector_type(4))) float f32x4;

__device__ __forceinline__ unsigned short f2bf(float f) {
  unsigned u = __builtin_bit_cast(unsigned, f);
  u += 0x7fffu + ((u >> 16) & 1u);
  return (unsigned short)(u >> 16);
}
__device__ __forceinline__ float bf2f(unsigned short h) {
  return __builtin_bit_cast(float, (unsigned)h << 16);
}

// ---------------------------------------------------------------------------
// Kernel 1 (fused): block-specialized.
//   blocks [0,256):      support u = x @ W^T (UNscaled, bf16) -> uT + urm
//   blocks [256, 8448):  rowsum  dinv[i] = rsqrt(sum_j adj[i,j] + 1)
// Support blocks are dispatched first so their VALU/LDS work overlaps the
// HBM-bound rowsum stream.
// ---------------------------------------------------------------------------
__global__ __launch_bounds__(256) void fused_pre_kernel(
    const float* __restrict__ adj, const float* __restrict__ x,
    const float* __restrict__ W, float* __restrict__ dinv,
    unsigned short* __restrict__ uT, unsigned short* __restrict__ urm) {
  __shared__ float4 xs[32 * 64];
  __shared__ float red[4];
  int tid = threadIdx.x;

  if (blockIdx.x >= 256) {
    // ---- rowsum branch ----
    int row = blockIdx.x - 256;
    const float4* r = (const float4*)(adj + (size_t)row * N_NODES);
    float s = 0.f;
#pragma unroll
    for (int it = 0; it < 8; ++it) {
      float4 v = r[tid + it * 256];
      s += (v.x + v.y) + (v.z + v.w);
    }
#pragma unroll
    for (int off = 32; off > 0; off >>= 1) s += __shfl_down(s, off);
    if ((tid & 63) == 0) red[tid >> 6] = s;
    __syncthreads();
    if (tid == 0) {
      float tot = red[0] + red[1] + red[2] + red[3] + 1.0f;
      dinv[row] = rsqrtf(tot);
    }
    return;
  }

  // ---- support branch: u[j,n] = sum_c x[j,c] * W[n,c] ----
  int j0 = blockIdx.x * 32;
  const float4* xg = (const float4*)(x + (size_t)j0 * DIM);
#pragma unroll
  for (int it = 0; it < 8; ++it) xs[tid + it * 256] = xg[tid + it * 256];
  __syncthreads();

  int n = tid;
  float acc[32];
#pragma unroll
  for (int j = 0; j < 32; ++j) acc[j] = 0.f;
  const float4* wrow = (const float4*)(W + (size_t)n * DIM);
#pragma unroll 1
  for (int cc = 0; cc < 4; ++cc) {
    float4 wr[16];
#pragma unroll
    for (int m = 0; m < 16; ++m) wr[m] = wrow[cc * 16 + m];
#pragma unroll
    for (int j = 0; j < 32; ++j) {
      float s = 0.f;
#pragma unroll
      for (int m = 0; m < 16; ++m) {
        float4 xv = xs[j * 64 + cc * 16 + m];  // LDS broadcast
        s += xv.x * wr[m].x + xv.y * wr[m].y + xv.z * wr[m].z + xv.w * wr[m].w;
      }
      acc[j] += s;
    }
  }
  size_t nrow = (size_t)n * N_NODES;
#pragma unroll
  for (int j = 0; j < 32; ++j) {
    unsigned short b = f2bf(acc[j]);
    uT[nrow + j0 + j] = b;                  // [n][j] — GEMM B operand
    urm[(size_t)(j0 + j) * DIM + n] = b;    // [j][n] — epilogue +I term
  }
}

// ---------------------------------------------------------------------------
// Kernel 2: split-K GEMM  part[s][i,k] = sum_{j in chunk} bf16(adj[i,j]*d_j)*u[j,k]
// Tile 64(M) x 256(N) x BK=32, 4 waves (each 64x64 = 4x4 frags, 16x16x32 bf16).
// Double-buffered LDS, ONE barrier per iter; next iter's globals issued before
// the MFMA section so the vmcnt wait lands after compute.
// ---------------------------------------------------------------------------
#define AROW 40  // padded LDS row (bf16): 80 B -> 2-way bank aliasing (free)
__global__ __launch_bounds__(256, 3) void gemm_kernel(
    const float* __restrict__ adj, const unsigned short* __restrict__ uT,
    const float* __restrict__ dinv, float* __restrict__ part, int KC) {
  __shared__ unsigned short Al[2][64 * AROW];
  __shared__ unsigned short Bl[2][256 * AROW];
  int tid = threadIdx.x;
  int lane = tid & 63, wave = tid >> 6;
  size_t i0 = (size_t)blockIdx.x * 64;
  int s = blockIdx.y;
  int kbase = s * KC;

  // staging roles
  int am = tid >> 2, ak = tid & 3;  // A: row i0+am, k-octet ak
  const float* ag = adj + (i0 + am) * (size_t)N_NODES + kbase + ak * 8;
  const float* dg = dinv + kbase + ak * 8;
  int bn = tid >> 2, bk = tid & 3;  // B: rows q*64+bn, k-octet bk
  const unsigned short* bg = uT + (size_t)bn * N_NODES + kbase + bk * 8;

  f32x4 acc[4][4];
#pragma unroll
  for (int mf = 0; mf < 4; ++mf)
#pragma unroll
    for (int nf = 0; nf < 4; ++nf) acc[mf][nf] = (f32x4){0.f, 0.f, 0.f, 0.f};

  int arow = lane & 15, akq = lane >> 4;

  float4 av0, av1, dv0, dv1;
  uint4 bv[4];

  auto load_g = [&](int kk) {
    av0 = *(const float4*)(ag + kk);
    av1 = *(const float4*)(ag + kk + 4);
    dv0 = *(const float4*)(dg + kk);
    dv1 = *(const float4*)(dg + kk + 4);
#pragma unroll
    for (int q = 0; q < 4; ++q)
      bv[q] = *(const uint4*)(bg + (size_t)q * 64 * N_NODES + kk);
  };
  auto store_s = [&](int buf) {
    unsigned p0 = f2bf(av0.x * dv0.x) | ((unsigned)f2bf(av0.y * dv0.y) << 16);
    unsigned p1 = f2bf(av0.z * dv0.z) | ((unsigned)f2bf(av0.w * dv0.w) << 16);
    unsigned p2 = f2bf(av1.x * dv1.x) | ((unsigned)f2bf(av1.y * dv1.y) << 16);
    unsigned p3 = f2bf(av1.z * dv1.z) | ((unsigned)f2bf(av1.w * dv1.w) << 16);
    *(uint4*)&Al[buf][am * AROW + ak * 8] = make_uint4(p0, p1, p2, p3);
#pragma unroll
    for (int q = 0; q < 4; ++q)
      *(uint4*)&Bl[buf][(q * 64 + bn) * AROW + bk * 8] = bv[q];
  };

  load_g(0);
  store_s(0);
  __syncthreads();

  for (int kk = 0; kk < KC; kk += 32) {
    int cur = (kk >> 5) & 1;
    bool more = (kk + 32) < KC;
    if (more) load_g(kk + 32);  // issue early; vmcnt wait lands after MFMAs

    bf16x8 a[4], b[4];
#pragma unroll
    for (int mf = 0; mf < 4; ++mf)
      a[mf] = *reinterpret_cast<const bf16x8*>(&Al[cur][(mf * 16 + arow) * AROW + akq * 8]);
#pragma unroll
    for (int nf = 0; nf < 4; ++nf)
      b[nf] = *reinterpret_cast<const bf16x8*>(&Bl[cur][(wave * 64 + nf * 16 + arow) * AROW + akq * 8]);
#pragma unroll
    for (int mf = 0; mf < 4; ++mf)
#pragma unroll
      for (int nf = 0; nf < 4; ++nf)
        acc[mf][nf] = __builtin_amdgcn_mfma_f32_16x16x32_bf16(a[mf], b[nf], acc[mf][nf], 0, 0, 0);

    if (more) store_s(cur ^ 1);
    __syncthreads();  // single barrier: separates reads(cur)/writes(cur^1) across iters
  }

  float* pb = part + (size_t)s * ((size_t)N_NODES * DIM);
  int crow = (lane >> 4) * 4;
  int ccol = lane & 15;
#pragma unroll
  for (int mf = 0; mf < 4; ++mf)
#pragma unroll
    for (int nf = 0; nf < 4; ++nf) {
      size_t rbase = (i0 + mf * 16 + crow) * (size_t)DIM + wave * 64 + nf * 16 + ccol;
#pragma unroll
      for (int r = 0; r < 4; ++r) pb[rbase + (size_t)r * DIM] = acc[mf][nf][r];
    }
}

// ---------------------------------------------------------------------------
// Kernel 3: out[i,k] = relu(d_i * sum_s part[s][i,k] + d_i^2 * u[i,k])
// ---------------------------------------------------------------------------
__global__ __launch_bounds__(256) void reduce_kernel(
    const float* __restrict__ part, const unsigned short* __restrict__ urm,
    const float* __restrict__ dinv, float* __restrict__ out, int S) {
  size_t idx = ((size_t)blockIdx.x * 256 + threadIdx.x) * 4;
  int i = (int)(idx >> 8);
  float4 v = *(const float4*)(part + idx);
  for (int s = 1; s < S; ++s) {
    float4 p = *(const float4*)(part + (size_t)s * ((size_t)N_NODES * DIM) + idx);
    v.x += p.x; v.y += p.y; v.z += p.z; v.w += p.w;
  }
  ushort4 t = *(const ushort4*)(urm + idx);
  float d = dinv[i];
  float dd = d * d;
  float4 o;
  o.x = fmaxf(0.f, d * v.x + dd * bf2f(t.x));
  o.y = fmaxf(0.f, d * v.y + dd * bf2f(t.y));
  o.z = fmaxf(0.f, d * v.z + dd * bf2f(t.z));
  o.w = fmaxf(0.f, d * v.w + dd * bf2f(t.w));
  *(float4*)(out + idx) = o;
}

// ---------------------------------------------------------------------------
extern "C" void kernel_launch(void* const* d_in, const int* in_sizes, int n_in,
                              void* d_out, int out_size, void* d_ws, size_t ws_size,
                              hipStream_t stream) {
  const float* x = (const float*)d_in[0];
  const float* adj = (const float*)d_in[1];
  const float* W = (const float*)d_in[2];
  float* out = (float*)d_out;
  char* ws = (char*)d_ws;

  // ws layout: dinv (32 KiB) | uT (4 MiB) | urm (4 MiB) | partials (S x 8 MiB)
  float* dinv = (float*)ws;
  unsigned short* uT = (unsigned short*)(ws + 32768);
  unsigned short* urm = (unsigned short*)(ws + 32768 + (size_t)N_NODES * DIM * 2);
  size_t base = 32768 + 2 * (size_t)N_NODES * DIM * 2;
  size_t pbytes = (size_t)N_NODES * DIM * 4;

  int S;
  float* part;
  if (base + 8 * pbytes <= ws_size) { S = 8; part = (float*)(ws + base); }
  else if (base + 4 * pbytes <= ws_size) { S = 4; part = (float*)(ws + base); }
  else if (base + 2 * pbytes <= ws_size) { S = 2; part = (float*)(ws + base); }
  else if (base + 1 * pbytes <= ws_size) { S = 1; part = (float*)(ws + base); }
  else { S = 1; part = out; }  // in-place fallback

  fused_pre_kernel<<<256 + N_NODES, 256, 0, stream>>>(adj, x, W, dinv, uT, urm);
  gemm_kernel<<<dim3(N_NODES / 64, S), 256, 0, stream>>>(adj, uT, dinv, part, N_NODES / S);
  reduce_kernel<<<(N_NODES * DIM) / 1024, 256, 0, stream>>>(part, urm, dinv, out, S);
}

// Round 3
// 479.980 us; speedup vs baseline: 1.3440x; 1.2533x over previous
//
#include <hip/hip_runtime.h>
#include <hip/hip_bf16.h>
#include <stdint.h>

#define N_NODES 8192
#define DIM 256

typedef __attribute__((ext_vector_type(8))) __bf16 bf16x8;
typedef __attribute__((ext_vector_type(4))) float f32x4;

__device__ __forceinline__ unsigned short f2bf(float f) {
  unsigned u = __builtin_bit_cast(unsigned, f);
  u += 0x7fffu + ((u >> 16) & 1u);
  return (unsigned short)(u >> 16);
}
__device__ __forceinline__ float bf2f(unsigned short h) {
  return __builtin_bit_cast(float, (unsigned)h << 16);
}
__device__ __forceinline__ unsigned pack2(float a, float b) {
  return (unsigned)f2bf(a) | ((unsigned)f2bf(b) << 16);
}

// ---------------------------------------------------------------------------
// Kernel 1 (fused, block-specialized):
//   blocks [0,256):      support u = x @ W^T (UNscaled, bf16) -> uT + urm
//   blocks [256, 8448):  rowsum  dinv[i] = rsqrt(sum_j adj[i,j] + 1)
// ---------------------------------------------------------------------------
__global__ __launch_bounds__(256) void fused_pre_kernel(
    const float* __restrict__ adj, const float* __restrict__ x,
    const float* __restrict__ W, float* __restrict__ dinv,
    unsigned short* __restrict__ uT, unsigned short* __restrict__ urm) {
  __shared__ float4 xs[32 * 64];
  __shared__ float red[4];
  int tid = threadIdx.x;

  if (blockIdx.x >= 256) {
    // ---- rowsum branch ----
    int row = blockIdx.x - 256;
    const float4* r = (const float4*)(adj + (size_t)row * N_NODES);
    float s = 0.f;
#pragma unroll
    for (int it = 0; it < 8; ++it) {
      float4 v = r[tid + it * 256];
      s += (v.x + v.y) + (v.z + v.w);
    }
#pragma unroll
    for (int off = 32; off > 0; off >>= 1) s += __shfl_down(s, off);
    if ((tid & 63) == 0) red[tid >> 6] = s;
    __syncthreads();
    if (tid == 0) {
      float tot = red[0] + red[1] + red[2] + red[3] + 1.0f;
      dinv[row] = rsqrtf(tot);
    }
    return;
  }

  // ---- support branch: u[j,n] = sum_c x[j,c] * W[n,c] ----
  int j0 = blockIdx.x * 32;
  const float4* xg = (const float4*)(x + (size_t)j0 * DIM);
#pragma unroll
  for (int it = 0; it < 8; ++it) xs[tid + it * 256] = xg[tid + it * 256];
  __syncthreads();

  int n = tid;
  float acc[32];
#pragma unroll
  for (int j = 0; j < 32; ++j) acc[j] = 0.f;
  const float4* wrow = (const float4*)(W + (size_t)n * DIM);
#pragma unroll 1
  for (int cc = 0; cc < 4; ++cc) {
    float4 wr[16];
#pragma unroll
    for (int m = 0; m < 16; ++m) wr[m] = wrow[cc * 16 + m];
#pragma unroll
    for (int j = 0; j < 32; ++j) {
      float s = 0.f;
#pragma unroll
      for (int m = 0; m < 16; ++m) {
        float4 xv = xs[j * 64 + cc * 16 + m];  // LDS broadcast
        s += xv.x * wr[m].x + xv.y * wr[m].y + xv.z * wr[m].z + xv.w * wr[m].w;
      }
      acc[j] += s;
    }
  }
  size_t nrow = (size_t)n * N_NODES;
#pragma unroll
  for (int j = 0; j < 32; ++j) {
    unsigned short b = f2bf(acc[j]);
    uT[nrow + j0 + j] = b;                  // [n][j] — GEMM B operand
    urm[(size_t)(j0 + j) * DIM + n] = b;    // [j][n] — epilogue +I term
  }
}

// ---------------------------------------------------------------------------
// Kernel 2: split-K GEMM  part[s][i,k] = sum_{j} bf16(adj[i,j]*d_j)*u[j,k]
// Tile 64(M) x 256(N full) x BK=32, 4 waves (each 64x64 = 4x4 frags of
// 16x16x32 bf16). DENSE staging maps: every global-load instruction covers
// contiguous full rows (8x128B for A, 16x64B for B) — the round-2 version
// fragmented each load into ~64 16-B transactions and was TA/latency-bound.
// Double-buffered LDS, one barrier/iter. Epilogue staged through LDS so
// part stores are full 1-KB rows (no partial-line RMW).
// ---------------------------------------------------------------------------
#define AROW 40  // padded LDS row (bf16): 80 B
__global__ __launch_bounds__(256) void gemm_kernel(
    const float* __restrict__ adj, const unsigned short* __restrict__ uT,
    const float* __restrict__ dinv, float* __restrict__ part, int KC) {
  __shared__ __align__(16) unsigned char smem[51200];
  unsigned short* Al = (unsigned short*)smem;            // [2][64*AROW]
  unsigned short* Bl = (unsigned short*)(smem + 10240);  // [2][256*AROW]
  float* Cs = (float*)smem;                              // epilogue (32 KB)

  int tid = threadIdx.x;
  int lane = tid & 63, wave = tid >> 6;
  size_t i0 = (size_t)blockIdx.x * 64;
  int s = blockIdx.y;
  int kbase = s * KC;

  // ---- dense staging maps ----
  int lr = tid >> 3, lo = tid & 7;  // A: rows lr, lr+32; 16-B piece lo
  const float* gA0 = adj + (i0 + lr) * (size_t)N_NODES + kbase + lo * 4;
  const float* gA1 = gA0 + (size_t)32 * N_NODES;
  const float* gD = dinv + kbase + lo * 4;
  int br = tid >> 2, bo = tid & 3;  // B: rows br,+64,+128,+192; 16-B piece bo
  const unsigned short* gB = uT + (size_t)br * N_NODES + kbase + bo * 8;

  f32x4 acc[4][4];
#pragma unroll
  for (int mf = 0; mf < 4; ++mf)
#pragma unroll
    for (int nf = 0; nf < 4; ++nf) acc[mf][nf] = (f32x4){0.f, 0.f, 0.f, 0.f};

  int arow = lane & 15, akq = lane >> 4;

  float4 av0, av1, dv;
  uint4 bv0, bv1, bv2, bv3;

  auto load_g = [&](int kk) {
    av0 = *(const float4*)(gA0 + kk);
    av1 = *(const float4*)(gA1 + kk);
    dv = *(const float4*)(gD + kk);
    bv0 = *(const uint4*)(gB + kk);
    bv1 = *(const uint4*)(gB + (size_t)64 * N_NODES + kk);
    bv2 = *(const uint4*)(gB + (size_t)128 * N_NODES + kk);
    bv3 = *(const uint4*)(gB + (size_t)192 * N_NODES + kk);
  };
  auto store_s = [&](int buf) {
    unsigned short* A = Al + buf * (64 * AROW);
    unsigned short* B = Bl + buf * (256 * AROW);
    uint2 w0, w1;
    w0.x = pack2(av0.x * dv.x, av0.y * dv.y);
    w0.y = pack2(av0.z * dv.z, av0.w * dv.w);
    w1.x = pack2(av1.x * dv.x, av1.y * dv.y);
    w1.y = pack2(av1.z * dv.z, av1.w * dv.w);
    *(uint2*)&A[lr * AROW + lo * 4] = w0;
    *(uint2*)&A[(lr + 32) * AROW + lo * 4] = w1;
    *(uint4*)&B[br * AROW + bo * 8] = bv0;
    *(uint4*)&B[(br + 64) * AROW + bo * 8] = bv1;
    *(uint4*)&B[(br + 128) * AROW + bo * 8] = bv2;
    *(uint4*)&B[(br + 192) * AROW + bo * 8] = bv3;
  };

  load_g(0);
  store_s(0);
  __syncthreads();

  int nIter = KC >> 5;
  for (int it = 0; it < nIter; ++it) {
    int cur = it & 1;
    if (it + 1 < nIter) load_g((it + 1) << 5);  // issue early

    const unsigned short* A = Al + cur * (64 * AROW);
    const unsigned short* B = Bl + cur * (256 * AROW);
    bf16x8 a[4], b[4];
#pragma unroll
    for (int mf = 0; mf < 4; ++mf)
      a[mf] = *reinterpret_cast<const bf16x8*>(&A[(mf * 16 + arow) * AROW + akq * 8]);
#pragma unroll
    for (int nf = 0; nf < 4; ++nf)
      b[nf] = *reinterpret_cast<const bf16x8*>(&B[(wave * 64 + nf * 16 + arow) * AROW + akq * 8]);
#pragma unroll
    for (int mf = 0; mf < 4; ++mf)
#pragma unroll
      for (int nf = 0; nf < 4; ++nf)
        acc[mf][nf] = __builtin_amdgcn_mfma_f32_16x16x32_bf16(a[mf], b[nf], acc[mf][nf], 0, 0, 0);

    if (it + 1 < nIter) store_s(cur ^ 1);
    __syncthreads();
  }

  // ---- epilogue: stage C through LDS, store full 1-KB rows ----
  float* pb = part + (size_t)s * ((size_t)N_NODES * DIM);
  int crow = (lane >> 4) * 4;
  int ccol = lane & 15;
#pragma unroll
  for (int p = 0; p < 2; ++p) {  // rows [p*32, p*32+32)
    if (p) __syncthreads();      // prev pass's Cs reads done
#pragma unroll
    for (int mf2 = 0; mf2 < 2; ++mf2) {
      int mf = p * 2 + mf2;
#pragma unroll
      for (int nf = 0; nf < 4; ++nf)
#pragma unroll
        for (int r = 0; r < 4; ++r)
          Cs[(mf2 * 16 + crow + r) * 256 + wave * 64 + nf * 16 + ccol] = acc[mf][nf][r];
    }
    __syncthreads();
#pragma unroll
    for (int it = 0; it < 8; ++it) {
      int f = tid + it * 256;
      int row = f >> 6, c4 = f & 63;
      *(float4*)(pb + (i0 + p * 32 + row) * (size_t)DIM + c4 * 4) =
          *(const float4*)(Cs + row * 256 + c4 * 4);
    }
  }
}

// ---------------------------------------------------------------------------
// Kernel 3: out[i,k] = relu(d_i * sum_s part[s][i,k] + d_i^2 * u[i,k])
// ---------------------------------------------------------------------------
__global__ __launch_bounds__(256) void reduce_kernel(
    const float* __restrict__ part, const unsigned short* __restrict__ urm,
    const float* __restrict__ dinv, float* __restrict__ out, int S) {
  size_t idx = ((size_t)blockIdx.x * 256 + threadIdx.x) * 4;
  int i = (int)(idx >> 8);
  float4 v = *(const float4*)(part + idx);
  for (int s = 1; s < S; ++s) {
    float4 p = *(const float4*)(part + (size_t)s * ((size_t)N_NODES * DIM) + idx);
    v.x += p.x; v.y += p.y; v.z += p.z; v.w += p.w;
  }
  ushort4 t = *(const ushort4*)(urm + idx);
  float d = dinv[i];
  float dd = d * d;
  float4 o;
  o.x = fmaxf(0.f, d * v.x + dd * bf2f(t.x));
  o.y = fmaxf(0.f, d * v.y + dd * bf2f(t.y));
  o.z = fmaxf(0.f, d * v.z + dd * bf2f(t.z));
  o.w = fmaxf(0.f, d * v.w + dd * bf2f(t.w));
  *(float4*)(out + idx) = o;
}

// ---------------------------------------------------------------------------
extern "C" void kernel_launch(void* const* d_in, const int* in_sizes, int n_in,
                              void* d_out, int out_size, void* d_ws, size_t ws_size,
                              hipStream_t stream) {
  const float* x = (const float*)d_in[0];
  const float* adj = (const float*)d_in[1];
  const float* W = (const float*)d_in[2];
  float* out = (float*)d_out;
  char* ws = (char*)d_ws;

  // ws layout: dinv (32 KiB) | uT (4 MiB) | urm (4 MiB) | partials (S x 8 MiB)
  float* dinv = (float*)ws;
  unsigned short* uT = (unsigned short*)(ws + 32768);
  unsigned short* urm = (unsigned short*)(ws + 32768 + (size_t)N_NODES * DIM * 2);
  size_t base = 32768 + 2 * (size_t)N_NODES * DIM * 2;
  size_t pbytes = (size_t)N_NODES * DIM * 4;

  int S;
  float* part;
  if (base + 8 * pbytes <= ws_size) { S = 8; part = (float*)(ws + base); }
  else if (base + 4 * pbytes <= ws_size) { S = 4; part = (float*)(ws + base); }
  else if (base + 2 * pbytes <= ws_size) { S = 2; part = (float*)(ws + base); }
  else if (base + 1 * pbytes <= ws_size) { S = 1; part = (float*)(ws + base); }
  else { S = 1; part = out; }  // in-place fallback

  fused_pre_kernel<<<256 + N_NODES, 256, 0, stream>>>(adj, x, W, dinv, uT, urm);
  gemm_kernel<<<dim3(N_NODES / 64, S), 256, 0, stream>>>(adj, uT, dinv, part, N_NODES / S);
  reduce_kernel<<<(N_NODES * DIM) / 1024, 256, 0, stream>>>(part, urm, dinv, out, S);
}